// Round 1
// baseline (126.612 us; speedup 1.0000x reference)
//
#include <hip/hip_runtime.h>

typedef __bf16 bf16_t;
typedef __bf16 bf16x8 __attribute__((ext_vector_type(8)));
typedef __bf16 bf16x4 __attribute__((ext_vector_type(4)));
typedef float  f32x4  __attribute__((ext_vector_type(4)));

#define B_  4
#define T_  4096
#define D_  1024
#define H_  64
#define BT  (B_*T_)

// exp2-domain: fold 1/sqrt(64) * log2(e) into q at weight-transpose time
#define QSCALE 0.1803368801111204f

// split-KV config: q-tiles of 16 rows, kv chunks of 512
#define KVCHUNK 512
#define NSLOT_PB 1152          // sum over 256 q-tiles of ceil((jt+1)/32)
#define NSLOT (4*NSLOT_PB)     // 4608

// workspace layout (bytes)
#define WS_KBF  0x000000u      // [BT][64] bf16        2 MB
#define WS_QBF  0x200000u      // [BT][64] bf16        2 MB (pre-scaled)
#define WS_VT   0x400000u      // [64][BT] bf16        2 MB (transposed V)
#define WS_WT   0x600000u      // [192][1024] bf16     384 KB
#define WS_POUT 0x680000u      // [NSLOT][16][64] bf16 9 MB
#define WS_PM   0xF80000u      // [NSLOT][16] f32      288 KB
#define WS_PL   0xFC8000u      // [NSLOT][16] f32      288 KB

#define MFMA(a,b,c) __builtin_amdgcn_mfma_f32_16x16x32_bf16((a),(b),(c),0,0,0)

// ---------------------------------------------------------------------------
// k0: transpose + bf16-convert weights. WT[n][k]: n 0..63=Wk, 64..127=Wq*QSCALE,
// 128..191=Wv. Thread layout k-major for coalesced reads of W*[k][n].
__global__ __launch_bounds__(256) void wtrans_kernel(
    const float* __restrict__ Wk, const float* __restrict__ Wq,
    const float* __restrict__ Wv, bf16_t* __restrict__ WT) {
  int idx = blockIdx.x * 256 + threadIdx.x;       // 0 .. 192*1024-1
  int k = idx / 192;
  int n = idx - k * 192;
  float v;
  if (n < 64)       v = Wk[k*64 + n];
  else if (n < 128) v = Wq[k*64 + (n-64)] * QSCALE;
  else              v = Wv[k*64 + (n-128)];
  WT[(size_t)n*1024 + k] = (bf16_t)v;
}

// ---------------------------------------------------------------------------
// k1: fused projection GEMM  [16384 x 1024] @ [1024 x 192] -> kbf,qbf,vT (bf16)
// 256 blocks x 256 thr (4 waves). Block: 64 rows, all 192 cols. x staged in
// LDS (bf16, +8 pad -> 2-way bank conflicts, free). WT read direct from L2.
__global__ __launch_bounds__(256) void proj_kernel(
    const float* __restrict__ x, const bf16_t* __restrict__ WT,
    bf16_t* __restrict__ kbf, bf16_t* __restrict__ qbf, bf16_t* __restrict__ vT) {
  __shared__ __bf16 xs[64][72];
  int tid  = threadIdx.x;
  int wv   = tid >> 6;
  int lane = tid & 63;
  int col  = lane & 15;
  int g    = lane >> 4;
  size_t m0 = (size_t)blockIdx.x * 64;
  int nbase = wv * 48;            // wave's 3 n-tiles

  f32x4 zero4 = {0.f, 0.f, 0.f, 0.f};
  f32x4 acc[4][3];
#pragma unroll
  for (int i = 0; i < 4; ++i)
#pragma unroll
    for (int j = 0; j < 3; ++j) acc[i][j] = zero4;

  int srow  = tid >> 2;           // staging: row 0..63
  int scol0 = (tid & 3) * 16;     // 4 float4 per thread

  for (int kc = 0; kc < 1024; kc += 64) {
    __syncthreads();              // WAR: previous iter reads done before overwrite
#pragma unroll
    for (int it = 0; it < 4; ++it) {
      int c = scol0 + it * 4;
      float4 v = *reinterpret_cast<const float4*>(x + (m0 + srow)*1024 + kc + c);
      bf16x4 pk = { (bf16_t)v.x, (bf16_t)v.y, (bf16_t)v.z, (bf16_t)v.w };
      *reinterpret_cast<bf16x4*>(&xs[srow][c]) = pk;
    }
    __syncthreads();
#pragma unroll
    for (int kk = 0; kk < 2; ++kk) {
      int ko = kk*32 + g*8;
      bf16x8 a0 = *(const bf16x8*)&xs[ 0 + col][ko];
      bf16x8 a1 = *(const bf16x8*)&xs[16 + col][ko];
      bf16x8 a2 = *(const bf16x8*)&xs[32 + col][ko];
      bf16x8 a3 = *(const bf16x8*)&xs[48 + col][ko];
#pragma unroll
      for (int nti = 0; nti < 3; ++nti) {
        const bf16_t* wp = WT + (size_t)(nbase + nti*16 + col)*1024 + kc + ko;
        bf16x8 bfr = *(const bf16x8*)wp;
        acc[0][nti] = MFMA(a0, bfr, acc[0][nti]);
        acc[1][nti] = MFMA(a1, bfr, acc[1][nti]);
        acc[2][nti] = MFMA(a2, bfr, acc[2][nti]);
        acc[3][nti] = MFMA(a3, bfr, acc[3][nti]);
      }
    }
  }
  // epilogue: D row = mt*16 + 4g + r, col = nbase + nti*16 + (lane&15)
#pragma unroll
  for (int mt = 0; mt < 4; ++mt) {
    size_t row0 = m0 + mt*16 + 4*g;
#pragma unroll
    for (int nti = 0; nti < 3; ++nti) {
      int n = nbase + nti*16 + col;
      f32x4 v = acc[mt][nti];
      if (n < 64) {
#pragma unroll
        for (int r = 0; r < 4; ++r) kbf[(row0 + r)*64 + n] = (bf16_t)v[r];
      } else if (n < 128) {
#pragma unroll
        for (int r = 0; r < 4; ++r) qbf[(row0 + r)*64 + (n-64)] = (bf16_t)v[r];
      } else {
        bf16x4 pk = { (bf16_t)v[0], (bf16_t)v[1], (bf16_t)v[2], (bf16_t)v[3] };
        *reinterpret_cast<bf16x4*>(&vT[(size_t)(n-128)*BT + row0]) = pk;
      }
    }
  }
}

// ---------------------------------------------------------------------------
// k2: split-KV flash attention. One wave per (batch, q-tile of 16, kv-chunk).
// exp2-domain online softmax; partial (O, m, l) to workspace.
__global__ __launch_bounds__(64) void attn_kernel(
    const bf16_t* __restrict__ qbf, const bf16_t* __restrict__ kbf,
    const bf16_t* __restrict__ vT, bf16_t* __restrict__ pout,
    float* __restrict__ pm, float* __restrict__ pl) {
  __shared__ __bf16 p_lds[16][72];
  int lane = threadIdx.x;
  int col = lane & 15;
  int g   = lane >> 4;

  // decode block -> (b, jt, c). per-batch slots grouped by a=jt/32 (a+1 chunks each)
  int bidx = blockIdx.x;
  int b = bidx / NSLOT_PB;
  int s = bidx - b * NSLOT_PB;
  int a = 0;
#pragma unroll
  for (int aa = 1; aa < 8; ++aa) if (16*aa*(aa+1) <= s) a = aa;
  int r2 = s - 16*a*(a+1);
  int qd = r2 / (a+1);
  int c  = r2 - qd*(a+1);
  int jt = 32*a + qd;

  int q0    = jt << 4;
  int kv_lo = c * KVCHUNK;
  int kv_hi = min(kv_lo + KVCHUNK, q0 + 16);

  const bf16_t* qp = qbf + ((size_t)(b*T_ + q0 + col))*H_ + g*8;
  bf16x8 aq0 = *(const bf16x8*)qp;
  bf16x8 aq1 = *(const bf16x8*)(qp + 32);

  f32x4 zero4 = {0.f, 0.f, 0.f, 0.f};
  f32x4 o[4];
  float m_[4], l_[4];
#pragma unroll
  for (int i = 0; i < 4; ++i) { o[i] = zero4; m_[i] = -1e30f; l_[i] = 0.f; }

  for (int kvt = kv_lo; kvt < kv_hi; kvt += 64) {
    // --- S = Q @ K^T (pre-scaled, exp2 domain) ---
    const bf16_t* kp0 = kbf + ((size_t)(b*T_ + kvt))*H_;
    bf16x8 bk[4][2];
#pragma unroll
    for (int nt = 0; nt < 4; ++nt) {
      const bf16_t* kp = kp0 + (size_t)(nt*16 + col)*H_ + g*8;
      bk[nt][0] = *(const bf16x8*)kp;
      bk[nt][1] = *(const bf16x8*)(kp + 32);
    }
    f32x4 s4[4];
#pragma unroll
    for (int nt = 0; nt < 4; ++nt) {
      s4[nt] = MFMA(aq0, bk[nt][0], zero4);
      s4[nt] = MFMA(aq1, bk[nt][1], s4[nt]);
    }
    // causal mask (only last tile can straddle the diagonal)
    if (kvt + 63 > q0) {
#pragma unroll
      for (int nt = 0; nt < 4; ++nt)
#pragma unroll
        for (int r = 0; r < 4; ++r) {
          int kv = kvt + nt*16 + col;
          int qr = q0 + 4*g + r;
          if (kv > qr) s4[nt][r] = -1e30f;
        }
    }
    // --- online softmax: row stats live replicated across the 16-lane group ---
    float sf[4], ts[4];
#pragma unroll
    for (int r = 0; r < 4; ++r) {
      float tm = fmaxf(fmaxf(s4[0][r], s4[1][r]), fmaxf(s4[2][r], s4[3][r]));
      tm = fmaxf(tm, __shfl_xor(tm, 1));
      tm = fmaxf(tm, __shfl_xor(tm, 2));
      tm = fmaxf(tm, __shfl_xor(tm, 4));
      tm = fmaxf(tm, __shfl_xor(tm, 8));
      float nm = fmaxf(m_[r], tm);
      sf[r] = exp2f(m_[r] - nm);
      m_[r] = nm;
      ts[r] = 0.f;
    }
#pragma unroll
    for (int nt = 0; nt < 4; ++nt)
#pragma unroll
      for (int r = 0; r < 4; ++r) {
        float p = exp2f(s4[nt][r] - m_[r]);   // masked entries -> exp2(-huge)=0
        ts[r] += p;
        p_lds[4*g + r][nt*16 + col] = (bf16_t)p;
      }
    __syncthreads();   // cross-lane LDS visibility within the wave
#pragma unroll
    for (int r = 0; r < 4; ++r) {
      float t2 = ts[r];
      t2 += __shfl_xor(t2, 1);
      t2 += __shfl_xor(t2, 2);
      t2 += __shfl_xor(t2, 4);
      t2 += __shfl_xor(t2, 8);
      l_[r] = l_[r]*sf[r] + t2;
    }
#pragma unroll
    for (int nt = 0; nt < 4; ++nt)
#pragma unroll
      for (int r = 0; r < 4; ++r) o[nt][r] *= sf[r];
    // --- O += P @ V  (A=P from LDS, B=V from transposed global) ---
    bf16x8 ap0 = *(const bf16x8*)&p_lds[col][g*8];
    bf16x8 ap1 = *(const bf16x8*)&p_lds[col][32 + g*8];
#pragma unroll
    for (int nt = 0; nt < 4; ++nt) {
      const bf16_t* vp = vT + (size_t)(nt*16 + col)*BT + b*T_ + kvt + g*8;
      bf16x8 bv0 = *(const bf16x8*)vp;
      bf16x8 bv1 = *(const bf16x8*)(vp + 32);
      o[nt] = MFMA(ap0, bv0, o[nt]);
      o[nt] = MFMA(ap1, bv1, o[nt]);
    }
    __syncthreads();   // WAR before next tile's P writes
  }
  // epilogue: partial O (bf16) + stats
  int slot = b*NSLOT_PB + (a+1)*(jt - 16*a) + c;
  bf16_t* po = pout + (size_t)slot * 1024;
#pragma unroll
  for (int nt = 0; nt < 4; ++nt)
#pragma unroll
    for (int r = 0; r < 4; ++r)
      po[(4*g + r)*64 + nt*16 + col] = (bf16_t)o[nt][r];
  if (col == 0) {
#pragma unroll
    for (int r = 0; r < 4; ++r) {
      pm[slot*16 + 4*g + r] = m_[r];
      pl[slot*16 + 4*g + r] = l_[r];
    }
  }
}

// ---------------------------------------------------------------------------
// k3: combine partials. One wave per output row; lane = h.
__global__ __launch_bounds__(256) void combine_kernel(
    const bf16_t* __restrict__ pout, const float* __restrict__ pm,
    const float* __restrict__ pl, float* __restrict__ out) {
  int w    = blockIdx.x * 4 + (threadIdx.x >> 6);   // row id 0..16383
  int lane = threadIdx.x & 63;
  int b  = w >> 12;
  int t  = w & 4095;
  int jt = t >> 4;
  int rl = t & 15;
  int a  = jt >> 5;
  int nch = a + 1;
  int slot0 = b*NSLOT_PB + nch*(jt - 16*a);

  float M = -1e30f;
  for (int c = 0; c < nch; ++c) M = fmaxf(M, pm[(slot0 + c)*16 + rl]);
  float av = 0.f, al = 0.f;
  for (int c = 0; c < nch; ++c) {
    float wgt = exp2f(pm[(slot0 + c)*16 + rl] - M);
    al += wgt * pl[(slot0 + c)*16 + rl];
    av += wgt * (float)pout[(size_t)(slot0 + c)*1024 + rl*64 + lane];
  }
  out[(size_t)w*64 + lane] = av / al;
}

// ---------------------------------------------------------------------------
extern "C" void kernel_launch(void* const* d_in, const int* in_sizes, int n_in,
                              void* d_out, int out_size, void* d_ws, size_t ws_size,
                              hipStream_t stream) {
  (void)in_sizes; (void)n_in; (void)out_size; (void)ws_size;
  const float* x  = (const float*)d_in[0];
  const float* Wk = (const float*)d_in[1];
  const float* Wq = (const float*)d_in[2];
  const float* Wv = (const float*)d_in[3];
  char* ws = (char*)d_ws;
  bf16_t* kbf  = (bf16_t*)(ws + WS_KBF);
  bf16_t* qbf  = (bf16_t*)(ws + WS_QBF);
  bf16_t* vT   = (bf16_t*)(ws + WS_VT);
  bf16_t* WT   = (bf16_t*)(ws + WS_WT);
  bf16_t* pout = (bf16_t*)(ws + WS_POUT);
  float*  pm   = (float*)(ws + WS_PM);
  float*  pl   = (float*)(ws + WS_PL);
  float*  outp = (float*)d_out;

  hipLaunchKernelGGL(wtrans_kernel, dim3(768),   dim3(256), 0, stream, Wk, Wq, Wv, WT);
  hipLaunchKernelGGL(proj_kernel,   dim3(256),   dim3(256), 0, stream, x, WT, kbf, qbf, vT);
  hipLaunchKernelGGL(attn_kernel,   dim3(NSLOT), dim3(64),  0, stream, qbf, kbf, vT, pout, pm, pl);
  hipLaunchKernelGGL(combine_kernel, dim3(4096), dim3(256), 0, stream, pout, pm, pl, outp);
}

// Round 2
// 97.067 us; speedup vs baseline: 1.3044x; 1.3044x over previous
//
#include <hip/hip_runtime.h>

typedef __bf16 bf16_t;
typedef __bf16 bf16x8 __attribute__((ext_vector_type(8)));
typedef __bf16 bf16x4 __attribute__((ext_vector_type(4)));
typedef float  f32x4  __attribute__((ext_vector_type(4)));

#define B_  4
#define T_  4096
#define D_  1024
#define H_  64
#define BT  (B_*T_)

// exp2-domain: fold 1/sqrt(64) * log2(e) into q at weight-transpose time
#define QSCALE 0.1803368801111204f

// split-KV: q-tiles of 64 rows, kv chunks of 512
// per batch: q-tile jt in [0,64), chunks = jt/8+1; total per batch = 288
#define NSLOT_PB 288
#define NSLOT (4*NSLOT_PB)     // 1152

// workspace layout (bytes)
#define WS_KBF  0x000000u      // [BT][64] bf16        2 MB
#define WS_QBF  0x200000u      // [BT][64] bf16        2 MB (pre-scaled)
#define WS_VT   0x400000u      // [64][BT] bf16        2 MB (transposed V)
#define WS_WT   0x600000u      // [192][1024] bf16     384 KB
#define WS_POUT 0x680000u      // [NSLOT][64][64] bf16 9 MB
#define WS_PM   0xF80000u      // [NSLOT][64] f32      288 KB
#define WS_PL   0xFC8000u      // [NSLOT][64] f32      288 KB

#define MFMA(a,b,c) __builtin_amdgcn_mfma_f32_16x16x32_bf16((a),(b),(c),0,0,0)

#define GLD16(gptr, lptr) __builtin_amdgcn_global_load_lds( \
    (const __attribute__((address_space(1))) unsigned int*)(gptr), \
    (__attribute__((address_space(3))) unsigned int*)(lptr), 16, 0, 0)

// ---------------------------------------------------------------------------
// k0: transpose + bf16-convert weights. WT[n][k]: n 0..63=Wk, 64..127=Wq*QSCALE,
// 128..191=Wv.
__global__ __launch_bounds__(256) void wtrans_kernel(
    const float* __restrict__ Wk, const float* __restrict__ Wq,
    const float* __restrict__ Wv, bf16_t* __restrict__ WT) {
  int idx = blockIdx.x * 256 + threadIdx.x;       // 0 .. 192*1024-1
  int k = idx / 192;
  int n = idx - k * 192;
  float v;
  if (n < 64)       v = Wk[k*64 + n];
  else if (n < 128) v = Wq[k*64 + (n-64)] * QSCALE;
  else              v = Wv[k*64 + (n-128)];
  WT[(size_t)n*1024 + k] = (bf16_t)v;
}

// ---------------------------------------------------------------------------
// k1: fused projection GEMM  [16384 x 1024] @ [1024 x 192] -> kbf,qbf,vT (bf16)
// 512 blocks x 256 thr (4 waves): block = 32 rows x 192 cols; wave wv = 48 cols.
// Register-staged x with 1-chunk software pipeline; LDS double-buffered.
__global__ __launch_bounds__(256) void proj_kernel(
    const float* __restrict__ x, const bf16_t* __restrict__ WT,
    bf16_t* __restrict__ kbf, bf16_t* __restrict__ qbf, bf16_t* __restrict__ vT) {
  __shared__ __bf16 xs[2][32][72];
  int tid  = threadIdx.x;
  int wv   = tid >> 6;
  int lane = tid & 63;
  int col  = lane & 15;
  int g    = lane >> 4;
  size_t m0 = (size_t)blockIdx.x * 32;
  int nbase = wv * 48;

  f32x4 zero4 = {0.f, 0.f, 0.f, 0.f};
  f32x4 acc[2][3];
#pragma unroll
  for (int i = 0; i < 2; ++i)
#pragma unroll
    for (int j = 0; j < 3; ++j) acc[i][j] = zero4;

  int srow = tid >> 3;            // 0..31
  int scol = (tid & 7) * 8;       // 8 f32 per thread
  const float* xrow = x + (m0 + srow)*1024 + scol;

  float4 r0 = *reinterpret_cast<const float4*>(xrow);
  float4 r1 = *reinterpret_cast<const float4*>(xrow + 4);
  {
    bf16x8 pk = { (bf16_t)r0.x,(bf16_t)r0.y,(bf16_t)r0.z,(bf16_t)r0.w,
                  (bf16_t)r1.x,(bf16_t)r1.y,(bf16_t)r1.z,(bf16_t)r1.w };
    *reinterpret_cast<bf16x8*>(&xs[0][srow][scol]) = pk;
  }

  for (int t = 0; t < 16; ++t) {
    int kc = t * 64;
    int cur = t & 1;
    __syncthreads();
    if (t < 15) {                 // issue next chunk's loads early
      r0 = *reinterpret_cast<const float4*>(xrow + kc + 64);
      r1 = *reinterpret_cast<const float4*>(xrow + kc + 68);
    }
#pragma unroll
    for (int kk = 0; kk < 2; ++kk) {
      int ko = kk*32 + g*8;
      bf16x8 a0 = *(const bf16x8*)&xs[cur][ 0 + col][ko];
      bf16x8 a1 = *(const bf16x8*)&xs[cur][16 + col][ko];
#pragma unroll
      for (int nti = 0; nti < 3; ++nti) {
        const bf16_t* wp = WT + (size_t)(nbase + nti*16 + col)*1024 + kc + ko;
        bf16x8 bfr = *(const bf16x8*)wp;
        acc[0][nti] = MFMA(a0, bfr, acc[0][nti]);
        acc[1][nti] = MFMA(a1, bfr, acc[1][nti]);
      }
    }
    if (t < 15) {
      bf16x8 pk = { (bf16_t)r0.x,(bf16_t)r0.y,(bf16_t)r0.z,(bf16_t)r0.w,
                    (bf16_t)r1.x,(bf16_t)r1.y,(bf16_t)r1.z,(bf16_t)r1.w };
      *reinterpret_cast<bf16x8*>(&xs[cur^1][srow][scol]) = pk;
    }
  }
  // epilogue: D row = m0 + mt*16 + 4g + r, col = nbase + nti*16 + (lane&15)
#pragma unroll
  for (int mt = 0; mt < 2; ++mt) {
    size_t row0 = m0 + mt*16 + 4*g;
#pragma unroll
    for (int nti = 0; nti < 3; ++nti) {
      int n = nbase + nti*16 + col;
      f32x4 v = acc[mt][nti];
      if (n < 64) {
#pragma unroll
        for (int r = 0; r < 4; ++r) kbf[(row0 + r)*64 + n] = (bf16_t)v[r];
      } else if (n < 128) {
#pragma unroll
        for (int r = 0; r < 4; ++r) qbf[(row0 + r)*64 + (n-64)] = (bf16_t)v[r];
      } else {
        bf16x4 pk = { (bf16_t)v[0], (bf16_t)v[1], (bf16_t)v[2], (bf16_t)v[3] };
        *reinterpret_cast<bf16x4*>(&vT[(size_t)(n-128)*BT + row0]) = pk;
      }
    }
  }
}

// ---------------------------------------------------------------------------
// k2: split-KV flash attention. Block = 4 waves, 64 q-rows (16/wave), kv-chunk
// 512. K/V staged in LDS via global_load_lds (double-buffered, XOR-swizzled
// through pre-swizzled global source). exp2-domain online softmax per wave.
__global__ __launch_bounds__(256) void attn_kernel(
    const bf16_t* __restrict__ qbf, const bf16_t* __restrict__ kbf,
    const bf16_t* __restrict__ vT, bf16_t* __restrict__ pout,
    float* __restrict__ pm, float* __restrict__ pl) {
  __shared__ __bf16 k_lds[2][64][64];
  __shared__ __bf16 v_lds[2][64][64];
  __shared__ __bf16 p_lds[4][16][72];
  int tid  = threadIdx.x;
  int wv   = tid >> 6;
  int lane = tid & 63;
  int col  = lane & 15;
  int g    = lane >> 4;

  // decode block -> (b, jt, c); group a = jt/8 has a+1 chunks per q-tile
  int bidx = blockIdx.x;
  int b = bidx / NSLOT_PB;
  int s = bidx - b * NSLOT_PB;
  int a = 0;
#pragma unroll
  for (int aa = 1; aa < 8; ++aa) if (4*aa*(aa+1) <= s) a = aa;
  int r2 = s - 4*a*(a+1);
  int qd = r2 / (a+1);
  int c  = r2 - qd*(a+1);
  int jt = 8*a + qd;

  int q0    = jt << 6;
  int kv_lo = c * 512;
  int kv_hi = min(kv_lo + 512, q0 + 64);
  int ntiles = (kv_hi - kv_lo) >> 6;

  const bf16_t* kb = kbf + (size_t)(b*T_)*64;

  // Q fragments (wave's 16 rows)
  int q0w = q0 + wv*16;
  const bf16_t* qp = qbf + ((size_t)(b*T_ + q0w + col))*64 + g*8;
  bf16x8 aq0 = *(const bf16x8*)qp;
  bf16x8 aq1 = *(const bf16x8*)(qp + 32);

  // staging decode: each wave stages rows [wv*16, wv*16+16) of K and V tiles
  int sr   = wv*16 + (lane >> 3);   // row for instr 0 (instr 1: +8)
  int ss   = lane & 7;              // 16B slot within 128B row
  int rm0  = lane >> 3;             // sr & 7
  int sl0  = (ss ^ rm0) * 8;        // swizzled source element offset
  const bf16_t* vrow0 = vT + (size_t)sr*BT + b*T_;
  const bf16_t* vrow1 = vT + (size_t)(sr+8)*BT + b*T_;

  f32x4 zero4 = {0.f, 0.f, 0.f, 0.f};
  f32x4 o[4];
  float m_[4], l_[4];
#pragma unroll
  for (int i = 0; i < 4; ++i) { o[i] = zero4; m_[i] = -1e30f; l_[i] = 0.f; }

  auto stage = [&](int buf, int kvt) {
    GLD16(kb + (size_t)(kvt + sr    )*64 + sl0, &k_lds[buf][wv*16    ][0]);
    GLD16(kb + (size_t)(kvt + sr + 8)*64 + sl0, &k_lds[buf][wv*16 + 8][0]);
    GLD16(vrow0 + kvt + sl0,                    &v_lds[buf][wv*16    ][0]);
    GLD16(vrow1 + kvt + sl0,                    &v_lds[buf][wv*16 + 8][0]);
  };

  stage(0, kv_lo);

  for (int t = 0; t < ntiles; ++t) {
    int cur = t & 1;
    int kvt = kv_lo + t*64;
    __syncthreads();                       // staged tile t visible to all waves
    if (t + 1 < ntiles) stage(cur ^ 1, kvt + 64);

    // --- S = Q @ K^T (pre-scaled, exp2 domain) ---
    f32x4 s4[4];
#pragma unroll
    for (int nt = 0; nt < 4; ++nt) {
      int row = nt*16 + col;
      const char* kr = (const char*)&k_lds[cur][row][0];
      bf16x8 b0 = *(const bf16x8*)(kr + ((g     ^ (row&7))*16));
      bf16x8 b1 = *(const bf16x8*)(kr + (((g+4) ^ (row&7))*16));
      s4[nt] = MFMA(aq0, b0, zero4);
      s4[nt] = MFMA(aq1, b1, s4[nt]);
    }
    // causal mask (only the diagonal tile straddles)
    if (kvt + 63 > q0w) {
#pragma unroll
      for (int nt = 0; nt < 4; ++nt)
#pragma unroll
        for (int r = 0; r < 4; ++r) {
          int kv = kvt + nt*16 + col;
          int qr = q0w + 4*g + r;
          if (kv > qr) s4[nt][r] = -1e30f;
        }
    }
    // --- online softmax (stats replicated across each 16-lane group) ---
    float sf[4], ts[4];
#pragma unroll
    for (int r = 0; r < 4; ++r) {
      float tm = fmaxf(fmaxf(s4[0][r], s4[1][r]), fmaxf(s4[2][r], s4[3][r]));
      tm = fmaxf(tm, __shfl_xor(tm, 1));
      tm = fmaxf(tm, __shfl_xor(tm, 2));
      tm = fmaxf(tm, __shfl_xor(tm, 4));
      tm = fmaxf(tm, __shfl_xor(tm, 8));
      float nm = fmaxf(m_[r], tm);
      sf[r] = exp2f(m_[r] - nm);
      m_[r] = nm;
      ts[r] = 0.f;
    }
#pragma unroll
    for (int nt = 0; nt < 4; ++nt)
#pragma unroll
      for (int r = 0; r < 4; ++r) {
        float p = exp2f(s4[nt][r] - m_[r]);
        ts[r] += p;
        p_lds[wv][4*g + r][nt*16 + col] = (bf16_t)p;
      }
#pragma unroll
    for (int r = 0; r < 4; ++r) {
      float t2 = ts[r];
      t2 += __shfl_xor(t2, 1);
      t2 += __shfl_xor(t2, 2);
      t2 += __shfl_xor(t2, 4);
      t2 += __shfl_xor(t2, 8);
      l_[r] = l_[r]*sf[r] + t2;
    }
#pragma unroll
    for (int nt = 0; nt < 4; ++nt)
#pragma unroll
      for (int r = 0; r < 4; ++r) o[nt][r] *= sf[r];
    // --- O += P @ V (A=P from per-wave LDS, B=V from swizzled LDS) ---
    bf16x8 ap0 = *(const bf16x8*)&p_lds[wv][col][g*8];
    bf16x8 ap1 = *(const bf16x8*)&p_lds[wv][col][32 + g*8];
#pragma unroll
    for (int nt = 0; nt < 4; ++nt) {
      int row = nt*16 + col;
      const char* vr = (const char*)&v_lds[cur][row][0];
      bf16x8 bv0 = *(const bf16x8*)(vr + ((g     ^ (row&7))*16));
      bf16x8 bv1 = *(const bf16x8*)(vr + (((g+4) ^ (row&7))*16));
      o[nt] = MFMA(ap0, bv0, o[nt]);
      o[nt] = MFMA(ap1, bv1, o[nt]);
    }
  }
  // epilogue: partial O (bf16) + stats; slot == blockIdx.x
  int slot = bidx;
  bf16_t* po = pout + (size_t)slot * 4096;
  int rb = wv*16 + 4*g;
#pragma unroll
  for (int nt = 0; nt < 4; ++nt)
#pragma unroll
    for (int r = 0; r < 4; ++r)
      po[(rb + r)*64 + nt*16 + col] = (bf16_t)o[nt][r];
  if (col == 0) {
#pragma unroll
    for (int r = 0; r < 4; ++r) {
      pm[slot*64 + rb + r] = m_[r];
      pl[slot*64 + rb + r] = l_[r];
    }
  }
}

// ---------------------------------------------------------------------------
// k3: combine partials. One wave per output row; lane = h.
__global__ __launch_bounds__(256) void combine_kernel(
    const bf16_t* __restrict__ pout, const float* __restrict__ pm,
    const float* __restrict__ pl, float* __restrict__ out) {
  int w    = blockIdx.x * 4 + (threadIdx.x >> 6);   // row id 0..16383
  int lane = threadIdx.x & 63;
  int b  = w >> 12;
  int t  = w & 4095;
  int jt = t >> 6;
  int rl = t & 63;
  int a  = jt >> 3;
  int nch = a + 1;
  int slot0 = b*NSLOT_PB + 4*a*(a+1) + (jt - 8*a)*(a+1);

  float M = -1e30f;
  for (int c = 0; c < nch; ++c) M = fmaxf(M, pm[(slot0 + c)*64 + rl]);
  float av = 0.f, al = 0.f;
  for (int c = 0; c < nch; ++c) {
    float wgt = exp2f(pm[(slot0 + c)*64 + rl] - M);
    al += wgt * pl[(slot0 + c)*64 + rl];
    av += wgt * (float)pout[(size_t)(slot0 + c)*4096 + rl*64 + lane];
  }
  out[(size_t)w*64 + lane] = av / al;
}

// ---------------------------------------------------------------------------
extern "C" void kernel_launch(void* const* d_in, const int* in_sizes, int n_in,
                              void* d_out, int out_size, void* d_ws, size_t ws_size,
                              hipStream_t stream) {
  (void)in_sizes; (void)n_in; (void)out_size; (void)ws_size;
  const float* x  = (const float*)d_in[0];
  const float* Wk = (const float*)d_in[1];
  const float* Wq = (const float*)d_in[2];
  const float* Wv = (const float*)d_in[3];
  char* ws = (char*)d_ws;
  bf16_t* kbf  = (bf16_t*)(ws + WS_KBF);
  bf16_t* qbf  = (bf16_t*)(ws + WS_QBF);
  bf16_t* vT   = (bf16_t*)(ws + WS_VT);
  bf16_t* WT   = (bf16_t*)(ws + WS_WT);
  bf16_t* pout = (bf16_t*)(ws + WS_POUT);
  float*  pm   = (float*)(ws + WS_PM);
  float*  pl   = (float*)(ws + WS_PL);
  float*  outp = (float*)d_out;

  hipLaunchKernelGGL(wtrans_kernel,  dim3(768),   dim3(256), 0, stream, Wk, Wq, Wv, WT);
  hipLaunchKernelGGL(proj_kernel,    dim3(512),   dim3(256), 0, stream, x, WT, kbf, qbf, vT);
  hipLaunchKernelGGL(attn_kernel,    dim3(NSLOT), dim3(256), 0, stream, qbf, kbf, vT, pout, pm, pl);
  hipLaunchKernelGGL(combine_kernel, dim3(4096),  dim3(256), 0, stream, pout, pm, pl, outp);
}